// Round 8
// baseline (1641.829 us; speedup 1.0000x reference)
//
#include <hip/hip_runtime.h>
#include <hip/hip_bf16.h>
#include <math.h>

// ---------------------------------------------------------------------------
// TransformerBlock: B=4, T=4096, C=768, DFF=3072, fp32 I/O.
// Round 8 (identical resubmit of r5/r6/r7; infra timeouts, kernel never ran):
// ws-size-safe chunked layout (floor ~61 MB, adaptive upward). Theory under
// test: r2/r3 core dumps were page faults from assuming 291 MB of workspace.
// x1 lives in d_out; attention & FFN processed in row chunks; LN1 per-batch.
// ---------------------------------------------------------------------------

typedef __hip_bfloat16 bf16;
using bf16x8 = __attribute__((ext_vector_type(8))) short;
using f32x4  = __attribute__((ext_vector_type(4))) float;

#define BDIM  4
#define TDIM  4096
#define CDIM  768
#define DFF   3072
#define BT    (BDIM * TDIM)

#define BM 128
#define BN 128
#define BK 32
#define LDK (BK + 8)            // pad: row stride 80 B (16B multiple)

enum { M_BF16 = 0, M_SCORES = 1, M_RESID = 2, M_GELU = 3 };

// ---------------------------------------------------------------------------
// GEMM: C[M,N] = A[M,K] * B[N,K]^T (row-major, dot over K). 128x128 tile,
// 4 waves. row0 = global row offset of A's first row (for causal logic).
// ---------------------------------------------------------------------------
template <int MODE, bool CAUSAL_SKIP, bool CAUSAL_K>
__global__ __launch_bounds__(256)
void gemm_bt(const bf16* __restrict__ A, int lda,
             const bf16* __restrict__ B, int ldb,
             void* __restrict__ Cout, int ldc,
             const float* __restrict__ res, int ldres,
             int K, float scale, int row0)
{
    const int m0 = blockIdx.y * BM;
    const int n0 = blockIdx.x * BN;
    if (CAUSAL_SKIP && n0 > row0 + m0 + BM - 1) return;

    __shared__ __align__(16) bf16 As[BM][LDK];
    __shared__ __align__(16) bf16 Bs[BN][LDK];

    const int tid  = threadIdx.x;
    const int lane = tid & 63;
    const int wid  = tid >> 6;
    const int wm   = (wid >> 1) * 64;
    const int wn   = (wid & 1) * 64;

    f32x4 acc[4][4];
    const f32x4 zero = {0.f, 0.f, 0.f, 0.f};
#pragma unroll
    for (int i = 0; i < 4; ++i)
#pragma unroll
        for (int j = 0; j < 4; ++j) acc[i][j] = zero;

    int kmax = K;
    if (CAUSAL_K) { const int kl = row0 + m0 + BM; kmax = (kl < K) ? kl : K; }

    const int r  = tid >> 2;
    const int c8 = (tid & 3) * 8;

    for (int k0 = 0; k0 < kmax; k0 += BK) {
        *(bf16x8*)&As[r][c8]      = *(const bf16x8*)&A[(size_t)(m0 + r) * lda + k0 + c8];
        *(bf16x8*)&As[r + 64][c8] = *(const bf16x8*)&A[(size_t)(m0 + r + 64) * lda + k0 + c8];
        *(bf16x8*)&Bs[r][c8]      = *(const bf16x8*)&B[(size_t)(n0 + r) * ldb + k0 + c8];
        *(bf16x8*)&Bs[r + 64][c8] = *(const bf16x8*)&B[(size_t)(n0 + r + 64) * ldb + k0 + c8];
        __syncthreads();

        const int fr = lane & 15;
        const int kq = (lane >> 4) * 8;
        bf16x8 af[4], bfr[4];
#pragma unroll
        for (int i = 0; i < 4; ++i) af[i]  = *(const bf16x8*)&As[wm + i * 16 + fr][kq];
#pragma unroll
        for (int i = 0; i < 4; ++i) bfr[i] = *(const bf16x8*)&Bs[wn + i * 16 + fr][kq];

#pragma unroll
        for (int mi = 0; mi < 4; ++mi)
#pragma unroll
            for (int ni = 0; ni < 4; ++ni)
                acc[mi][ni] = __builtin_amdgcn_mfma_f32_16x16x32_bf16(af[mi], bfr[ni], acc[mi][ni], 0, 0, 0);
        __syncthreads();
    }

    const int fr = lane & 15;
    const int fq = (lane >> 4) * 4;
#pragma unroll
    for (int mi = 0; mi < 4; ++mi)
#pragma unroll
        for (int ni = 0; ni < 4; ++ni)
#pragma unroll
            for (int j = 0; j < 4; ++j) {
                const int row = m0 + wm + mi * 16 + fq + j;   // local row
                const int col = n0 + wn + ni * 16 + fr;
                const float v = acc[mi][ni][j];
                if (MODE == M_SCORES) {
                    ((float*)Cout)[(size_t)row * ldc + col] = v * scale;
                } else if (MODE == M_BF16) {
                    ((bf16*)Cout)[(size_t)row * ldc + col] = __float2bfloat16(v);
                } else if (MODE == M_GELU) {
                    const float g = 0.5f * v * (1.f + erff(v * 0.70710678118f));
                    ((bf16*)Cout)[(size_t)row * ldc + col] = __float2bfloat16(g);
                } else {
                    ((float*)Cout)[(size_t)row * ldc + col] = v + res[(size_t)row * ldres + col];
                }
            }
}

// ---------------------------------------------------------------------------
__global__ __launch_bounds__(256)
void ln_bf16(const float* __restrict__ x, const float* __restrict__ g,
             const float* __restrict__ b, bf16* __restrict__ out)
{
    const int row = blockIdx.x;
    const float* xr = x + (size_t)row * CDIM;
    const int tid = threadIdx.x;

    float v[3], s = 0.f, ss = 0.f;
#pragma unroll
    for (int i = 0; i < 3; ++i) {
        v[i] = xr[tid + i * 256];
        s += v[i];
        ss += v[i] * v[i];
    }
    __shared__ float sm[8];
#pragma unroll
    for (int o = 32; o >= 1; o >>= 1) {
        s  += __shfl_xor(s, o);
        ss += __shfl_xor(ss, o);
    }
    const int wid = tid >> 6, lane = tid & 63;
    if (lane == 0) { sm[wid] = s; sm[4 + wid] = ss; }
    __syncthreads();
    s  = sm[0] + sm[1] + sm[2] + sm[3];
    ss = sm[4] + sm[5] + sm[6] + sm[7];
    const float mu  = s * (1.f / CDIM);
    const float var = ss * (1.f / CDIM) - mu * mu;
    const float rs  = rsqrtf(var + 1e-5f);
#pragma unroll
    for (int i = 0; i < 3; ++i) {
        const int c = tid + i * 256;
        out[(size_t)row * CDIM + c] = __float2bfloat16((v[i] - mu) * rs * g[c] + b[c]);
    }
}

// ---------------------------------------------------------------------------
// Transpose V from one batch's qkv rows -> vt[c][s]
// ---------------------------------------------------------------------------
__global__ void vtrans(const bf16* __restrict__ qkvb, bf16* __restrict__ vt)
{
    __shared__ __align__(16) bf16 t[32][33];
    const int s0 = blockIdx.x * 32;
    const int c0 = blockIdx.y * 32;
    const int tx = threadIdx.x, ty = threadIdx.y;  // 32 x 8
#pragma unroll
    for (int i = 0; i < 4; ++i)
        t[ty + i * 8][tx] = qkvb[(size_t)(s0 + ty + i * 8) * (3 * CDIM) + 2 * CDIM + c0 + tx];
    __syncthreads();
#pragma unroll
    for (int i = 0; i < 4; ++i)
        vt[(size_t)(c0 + ty + i * 8) * TDIM + s0 + tx] = t[tx][ty + i * 8];
}

// ---------------------------------------------------------------------------
// Causal softmax; block x = local row, global row = q0 + local.
// ---------------------------------------------------------------------------
__global__ __launch_bounds__(256)
void softmax_row(const float* __restrict__ sc, bf16* __restrict__ p, int q0)
{
    const int tl  = blockIdx.x;
    const int len = q0 + tl + 1;
    const int tid = threadIdx.x;

    float v[16];
    float m = -3.4e38f;
#pragma unroll
    for (int i = 0; i < 16; ++i) {
        const int j = tid + i * 256;
        v[i] = (j < len) ? sc[(size_t)tl * TDIM + j] : -3.4e38f;
        m = fmaxf(m, v[i]);
    }
    __shared__ float sm[8];
#pragma unroll
    for (int o = 32; o >= 1; o >>= 1) m = fmaxf(m, __shfl_xor(m, o));
    const int wid = tid >> 6, lane = tid & 63;
    if (lane == 0) sm[wid] = m;
    __syncthreads();
    m = fmaxf(fmaxf(sm[0], sm[1]), fmaxf(sm[2], sm[3]));

    float e[16], l = 0.f;
#pragma unroll
    for (int i = 0; i < 16; ++i) {
        const int j = tid + i * 256;
        e[i] = (j < len) ? expf(v[i] - m) : 0.f;
        l += e[i];
    }
#pragma unroll
    for (int o = 32; o >= 1; o >>= 1) l += __shfl_xor(l, o);
    if (lane == 0) sm[4 + wid] = l;
    __syncthreads();
    l = sm[4] + sm[5] + sm[6] + sm[7];
    const float inv = 1.f / l;
#pragma unroll
    for (int i = 0; i < 16; ++i) {
        const int j = tid + i * 256;
        p[(size_t)tl * TDIM + j] = __float2bfloat16(e[i] * inv);
    }
}

// ---------------------------------------------------------------------------
__global__ void cvt_bf16(const float* __restrict__ in, bf16* __restrict__ out, int n)
{
    int i = blockIdx.x * blockDim.x + threadIdx.x;
    const int stride = gridDim.x * blockDim.x;
    for (; i < n; i += stride) out[i] = __float2bfloat16(in[i]);
}

// Diagnostic fallback: out = x (runs only if ws_size below floor; finite
// absmax instead of a fault tells us ws was the problem).
__global__ void copy_f32(const float* __restrict__ in, float* __restrict__ out, int n)
{
    int i = blockIdx.x * blockDim.x + threadIdx.x;
    const int stride = gridDim.x * blockDim.x;
    for (; i < n; i += stride) out[i] = in[i];
}

// ---------------------------------------------------------------------------
extern "C" void kernel_launch(void* const* d_in, const int* in_sizes, int n_in,
                              void* d_out, int out_size, void* d_ws, size_t ws_size,
                              hipStream_t stream)
{
    const float* x      = (const float*)d_in[0];
    const float* ln1_g  = (const float*)d_in[1];
    const float* ln1_b  = (const float*)d_in[2];
    const float* qkv_w  = (const float*)d_in[3];
    const float* proj_w = (const float*)d_in[4];
    const float* ln2_g  = (const float*)d_in[5];
    const float* ln2_b  = (const float*)d_in[6];
    const float* w1     = (const float*)d_in[7];
    const float* w2     = (const float*)d_in[8];
    float* outf = (float*)d_out;

    char* ws = (char*)d_ws;
    size_t off = 0;
    auto alloc = [&](size_t bytes) -> void* {
        void* p = ws + off;
        off += (bytes + 255) & ~(size_t)255;
        return p;
    };

    // ---- fixed allocations (~53 MB) ----
    bf16* wqkv_b  = (bf16*)alloc((size_t)3 * CDIM * CDIM * 2);  // 3.4 MB
    bf16* wproj_b = (bf16*)alloc((size_t)CDIM * CDIM * 2);      // 1.1 MB
    bf16* w1_b    = (bf16*)alloc((size_t)DFF * CDIM * 2);       // 4.5 MB
    bf16* w2_b    = (bf16*)alloc((size_t)CDIM * DFF * 2);       // 4.5 MB
    bf16* hb      = (bf16*)alloc((size_t)TDIM * CDIM * 2);      // per-batch LN1 out, 6 MB
    bf16* qkv_b   = (bf16*)alloc((size_t)TDIM * 3 * CDIM * 2);  // per-batch qkv, 18.9 MB
    bf16* vt      = (bf16*)alloc((size_t)CDIM * TDIM * 2);      // per-batch V^T, 6 MB
    bf16* attn_b  = (bf16*)alloc((size_t)TDIM * CDIM * 2);      // per-batch attn, 6 MB

    const size_t avail = (ws_size > off) ? (ws_size - off) : 0;
    const size_t floor_need = (size_t)1024 * (CDIM + DFF) * 2;  // ~7.9 MB
    if (avail < floor_need) {
        // ws too small for the real path — diagnostic fallback.
        copy_f32<<<2048, 256, 0, stream>>>(x, outf, BT * CDIM);
        return;
    }

    // ---- adaptive chunk sizes ----
    const int CH  = (avail >= (size_t)2048 * TDIM * 6) ? 2048
                  : (avail >= (size_t)1024 * TDIM * 6) ? 1024
                  : (avail >= (size_t)512  * TDIM * 6) ? 512 : 256;
    const int CHF = (avail >= (size_t)4096 * (CDIM + DFF) * 2) ? 4096
                  : (avail >= (size_t)2048 * (CDIM + DFF) * 2) ? 2048 : 1024;
    const size_t rA = (size_t)CH * TDIM * 6;            // scores f32 + P bf16
    const size_t rF = (size_t)CHF * (CDIM + DFF) * 2;   // h2 + ff chunks
    char* region = (char*)alloc(rA > rF ? rA : rF);

    float* scores = (float*)region;
    bf16*  pbuf   = (bf16*)(region + (size_t)CH * TDIM * 4);
    bf16*  h2c    = (bf16*)region;
    bf16*  ffc    = (bf16*)(region + (size_t)CHF * CDIM * 2);

    const float scale = 0.036084391824352f;   // 1/sqrt(768)

    // 1) weights -> bf16
    cvt_bf16<<<1024, 256, 0, stream>>>(qkv_w,  wqkv_b,  3 * CDIM * CDIM);
    cvt_bf16<<<1024, 256, 0, stream>>>(proj_w, wproj_b, CDIM * CDIM);
    cvt_bf16<<<1024, 256, 0, stream>>>(w1,     w1_b,    DFF * CDIM);
    cvt_bf16<<<1024, 256, 0, stream>>>(w2,     w2_b,    CDIM * DFF);

    // 2) attention, one batch at a time
    for (int b = 0; b < BDIM; ++b) {
        const float* xb = x + (size_t)b * TDIM * CDIM;
        // LN1 for this batch
        ln_bf16<<<TDIM, 256, 0, stream>>>(xb, ln1_g, ln1_b, hb);
        // qkv_b = h_b @ wqkv^T   [4096, 2304]
        gemm_bt<M_BF16, false, false><<<dim3((3 * CDIM) / BN, TDIM / BM), 256, 0, stream>>>(
            hb, CDIM, wqkv_b, CDIM, qkv_b, 3 * CDIM, nullptr, 0, CDIM, 0.f, 0);
        // V^T
        vtrans<<<dim3(TDIM / 32, CDIM / 32), dim3(32, 8), 0, stream>>>(qkv_b, vt);

        for (int q0 = 0; q0 < TDIM; q0 += CH) {
            const bf16* qc = qkv_b + (size_t)q0 * 3 * CDIM;
            // scores chunk [CH, 4096]
            gemm_bt<M_SCORES, true, false><<<dim3(TDIM / BN, CH / BM), 256, 0, stream>>>(
                qc, 3 * CDIM, qkv_b + CDIM, 3 * CDIM, scores, TDIM, nullptr, 0, CDIM, scale, q0);
            // softmax chunk
            softmax_row<<<CH, 256, 0, stream>>>(scores, pbuf, q0);
            // attn chunk = P @ (V^T)^T  [CH, 768], causal K-limit
            gemm_bt<M_BF16, false, true><<<dim3(CDIM / BN, CH / BM), 256, 0, stream>>>(
                pbuf, TDIM, vt, TDIM, attn_b + (size_t)q0 * CDIM, CDIM,
                nullptr, 0, TDIM, 0.f, q0);
        }
        // x1_b = x_b + attn_b @ proj^T  -> d_out rows of batch b
        gemm_bt<M_RESID, false, false><<<dim3(CDIM / BN, TDIM / BM), 256, 0, stream>>>(
            attn_b, CDIM, wproj_b, CDIM, outf + (size_t)b * TDIM * CDIM, CDIM,
            xb, CDIM, CDIM, 0.f, 0);
    }

    // 3) FFN in row chunks; x1 lives in d_out, overwritten in place.
    for (int f0 = 0; f0 < BT; f0 += CHF) {
        const float* x1c = outf + (size_t)f0 * CDIM;
        ln_bf16<<<CHF, 256, 0, stream>>>(x1c, ln2_g, ln2_b, h2c);
        gemm_bt<M_GELU, false, false><<<dim3(DFF / BN, CHF / BM), 256, 0, stream>>>(
            h2c, CDIM, w1_b, CDIM, ffc, DFF, nullptr, 0, CDIM, 0.f, 0);
        gemm_bt<M_RESID, false, false><<<dim3(CDIM / BN, CHF / BM), 256, 0, stream>>>(
            ffc, DFF, w2_b, DFF, outf + (size_t)f0 * CDIM, CDIM,
            x1c, CDIM, DFF, 0.f, 0);
    }
}